// Round 5
// baseline (62.787 us; speedup 1.0000x reference)
//
#include <hip/hip_runtime.h>

// MesoLayer — flat-chunk staged, 3-buffer 2-deep counted-vmcnt pipeline,
// ONE barrier per phase.
// Block = 256 threads = 256 rows, 16 chunks x 16 rows. Block's x panel
// (256*390 fl) is contiguous -> staged flat as float4 via global_load_lds
// (per-lane LDS ptrs; wave-uniform-base contract). Per-phase schedule:
//   wait vmcnt(exact, per-wave) -> lgkmcnt(0) -> s_barrier
//   -> stage(p+2) -> flush(p-1) -> compute(p)
// Chunk p+1 and p+2 loads stay in flight across the barrier (never drained).
// Per-wave VMEM/phase: wave0 = 7 loads + 1 store, waves1-3 = 6 + 1 -> exact
// wait immediates differ per wave (wave-uniform branch).

#define GLL16(gp, lp)                                                   \
  __builtin_amdgcn_global_load_lds(                                     \
      (const __attribute__((address_space(1))) void*)(gp),              \
      (__attribute__((address_space(3))) void*)(lp), 16, 0, 0)

// One segment for one row from LDS. 16 active lanes per seg-group; row
// stride 390 floats (390%32=6 -> banks (r*6+c)%32 distinct: conflict-free).
template<int L>
__device__ __forceinline__ void seg_compute(const float* bp,
                                            const float (&M)[5][5],
                                            float* ob) {
  float ss[5] = {0.f, 0.f, 0.f, 0.f, 0.f};
#pragma unroll
  for (int j = 0; j < L; ++j)
#pragma unroll
    for (int g = 0; g < 5; ++g) ss[g] += bp[j * 5 + g];

  float v[5];
#pragma unroll
  for (int g = 0; g < 5; ++g) {
    float a = 0.f;
#pragma unroll
    for (int h = 0; h < 5; ++h) a += M[g][h] * ss[h];
    v[g] = a;
  }

  float sc[L];
  float m = -1e30f;
#pragma unroll
  for (int j = 0; j < L; ++j) {
    float a = 0.f;
#pragma unroll
    for (int g = 0; g < 5; ++g) a += bp[j * 5 + g] * v[g];
    sc[j] = a;
    m = fmaxf(m, a);
  }

  float d = 0.f, p5[5] = {0.f, 0.f, 0.f, 0.f, 0.f};
#pragma unroll
  for (int j = 0; j < L; ++j) {
    float e = __expf(sc[j] - m);
    d += e;
#pragma unroll
    for (int g = 0; g < 5; ++g) p5[g] += e * bp[j * 5 + g];
  }
  float inv = 1.0f / d;
#pragma unroll
  for (int g = 0; g < 5; ++g) ob[g] = p5[g] * inv;
}

// LDS (floats): buf0 @0, buf1 @6240, buf2 @12480 (1560 fl4 each, chunk c ->
// buf c%3); outbuf @18720 (2 x 560 fl). Total 79360 B -> 2 blocks/CU.
__global__ __launch_bounds__(256, 2) void meso_kernel(
    const float* __restrict__ x, const float* __restrict__ w,
    float* __restrict__ out) {
  __shared__ __align__(16) float smf[19840];
  float4* sm4 = (float4*)smf;
  const int t = threadIdx.x;
  const int wv = t >> 6, ln = t & 63, sg = ln >> 4, r = ln & 15;
  const size_t blk = blockIdx.x;
  const float4* xp4 = (const float4*)x + blk * 24960;  // 256*390/4
  float4* o4 = (float4*)out + blk * 2240;              // 256*35/4

  // M = W W^T first: uniform scalar (SMEM) loads, fully consumed before the
  // loop, so no stray VMEM residue perturbs the counted waits.
  float W[5][10];
#pragma unroll
  for (int g = 0; g < 5; ++g)
#pragma unroll
    for (int h = 0; h < 10; ++h) W[g][h] = w[g * 10 + h];
  float M[5][5];
#pragma unroll
  for (int g = 0; g < 5; ++g)
#pragma unroll
    for (int gp = 0; gp < 5; ++gp) {
      float a = 0.f;
#pragma unroll
      for (int h = 0; h < 10; ++h) a += W[g][h] * W[gp][h];
      M[g][gp] = a;
    }

  // Stage chunk c (1560 fl4) into buf b. 6 full-wave loads (per-lane LDS ptr
  // -> readfirstlane base i*256+64*wv, HW adds lane*16B) + wave0-only tail
  // (24 active lanes; inactive lanes write nothing -> no pad needed).
  auto stage = [&](int c, int b) {
    const float4* g = xp4 + c * 1560;
    float4* l = sm4 + b * 1560;
#pragma unroll
    for (int i = 0; i < 6; ++i) GLL16(g + i * 256 + t, l + i * 256 + t);
    if (t < 24) GLL16(g + 1536 + t, l + 1536 + t);
  };

  stage(0, 0);
  stage(1, 1);

  int bcur = 0;  // p % 3
#pragma unroll 1
  for (int p = 0; p < 16; ++p) {
    // Exact per-wave counted wait for chunk p (ops issued after chunk p's
    // last load: see per-phase accounting; wave0 has +1 load per chunk).
    if (p < 2) {
      if (wv == 0) asm volatile("s_waitcnt vmcnt(7)" ::: "memory");
      else         asm volatile("s_waitcnt vmcnt(6)" ::: "memory");
    } else if (p == 2) {
      if (wv == 0) asm volatile("s_waitcnt vmcnt(8)" ::: "memory");
      else         asm volatile("s_waitcnt vmcnt(7)" ::: "memory");
    } else if (p < 15) {
      if (wv == 0) asm volatile("s_waitcnt vmcnt(9)" ::: "memory");
      else         asm volatile("s_waitcnt vmcnt(8)" ::: "memory");
    } else {
      asm volatile("s_waitcnt vmcnt(2)" ::: "memory");
    }
    asm volatile("s_waitcnt lgkmcnt(0)" ::: "memory");
    __builtin_amdgcn_s_barrier();
    // Post-barrier invariants: chunk p fully in buf[p%3]; compute(p-1) LDS
    // reads drained (so buf[(p+2)%3] is reusable); outbuf[(p-1)&1] complete.

    if (p < 14) {
      int bn = bcur + 2; if (bn >= 3) bn -= 3;
      stage(p + 2, bn);
    }
    if (p > 0 && ln < 35) {
      // flush(p-1): each wave stores its own 35 fl4 -> 1 store instr/wave.
      o4[(size_t)(p - 1) * 140 + wv * 35 + ln] =
          sm4[4680 + ((p - 1) & 1) * 140 + wv * 35 + ln];
    }

    {
      const float* bp = smf + bcur * 6240 + r * 390;
      float* ob = smf + 18720 + (p & 1) * 560 + r * 35;
      if (wv == 0) {
        if (sg == 0) seg_compute<25>(bp + 115, M, ob + 15);
      } else if (wv == 1) {
        if (sg == 0)      seg_compute<12>(bp + 330, M, ob + 30);
        else if (sg == 1) seg_compute<5 >(bp + 0,   M, ob + 0);
      } else if (wv == 2) {
        if (sg == 0)      seg_compute<9 >(bp + 25,  M, ob + 5);
        else if (sg == 1) seg_compute<9 >(bp + 70,  M, ob + 10);
      } else {
        if (sg == 0)      seg_compute<9 >(bp + 240, M, ob + 20);
        else if (sg == 1) seg_compute<9 >(bp + 285, M, ob + 25);
      }
    }
    ++bcur; if (bcur >= 3) bcur = 0;
  }

  asm volatile("s_waitcnt lgkmcnt(0)" ::: "memory");
  __builtin_amdgcn_s_barrier();
  if (ln < 35)
    o4[15 * 140 + wv * 35 + ln] = sm4[4680 + 140 + wv * 35 + ln];
}

extern "C" void kernel_launch(void* const* d_in, const int* in_sizes, int n_in,
                              void* d_out, int out_size, void* d_ws, size_t ws_size,
                              hipStream_t stream) {
  const float* x = (const float*)d_in[0];
  const float* w = (const float*)d_in[1];
  float* out = (float*)d_out;
  int B = in_sizes[0] / 390;  // 131072
  int grid = B / 256;         // 512 blocks = 2/CU, all resident
  meso_kernel<<<grid, 256, 0, stream>>>(x, w, out);
}

// Round 6
// 51.333 us; speedup vs baseline: 1.2231x; 1.2231x over previous
//
#include <hip/hip_runtime.h>

// MesoLayer — R4's 3-buffer counted-vmcnt pipeline + 64-lane register-batched
// segment compute.
// Block = 256 threads = 256 rows, 16 chunks x 16 rows, staged flat as float4
// via global_load_lds (per-lane LDS ptrs). Per phase:
//   wait vmcnt(exact per-wave) -> lgkmcnt(0) -> s_barrier
//   -> stage(p+2) -> flush(p-1) -> compute(p)
// Compute: each segment uses ALL 64 lanes: lane (r,q) = (ln&15, ln>>4) covers
// row r, j in {q, q+4, ...}. Elements are read ONCE into registers (batched
// independent ds_reads), per-lane online-softmax partials, 4-way cross-lane
// merge via __shfl_xor(16/32). No exec-mask waste, no read-use chains.

#define GLL16(gp, lp)                                                   \
  __builtin_amdgcn_global_load_lds(                                     \
      (const __attribute__((address_space(1))) void*)(gp),              \
      (__attribute__((address_space(3))) void*)(lp), 16, 0, 0)

// 64-lane segment: bp = LDS row base (r applied), ob = LDS out row base.
// Lane-group q handles j = q + 4k. Clamped trailing j is masked (s=0, a=-inf).
template<int L, int SEGOFF, int OUTOFF>
__device__ __forceinline__ void seg64(const float* __restrict__ bp, int q,
                                      const float (&M)[5][5],
                                      float* __restrict__ ob) {
  constexpr int NJ = (L + 3) / 4;
  const bool lastv = (q + 4 * (NJ - 1)) < L;

  float s[NJ][5];
#pragma unroll
  for (int k = 0; k < NJ; ++k) {
    int j = q + 4 * k;
    if (j > L - 1) j = L - 1;  // only last k can clamp
#pragma unroll
    for (int g = 0; g < 5; ++g) s[k][g] = bp[SEGOFF + j * 5 + g];
  }
#pragma unroll
  for (int g = 0; g < 5; ++g) s[NJ - 1][g] = lastv ? s[NJ - 1][g] : 0.f;

  // local column sums, then 4-way cross-q reduce -> full subsum (all lanes)
  float ssl[5];
#pragma unroll
  for (int g = 0; g < 5; ++g) {
    float a = s[0][g];
#pragma unroll
    for (int k = 1; k < NJ; ++k) a += s[k][g];
    ssl[g] = a;
  }
#pragma unroll
  for (int g = 0; g < 5; ++g) {
    ssl[g] += __shfl_xor(ssl[g], 16, 64);
    ssl[g] += __shfl_xor(ssl[g], 32, 64);
  }

  float v[5];
#pragma unroll
  for (int g = 0; g < 5; ++g) {
    float a = M[g][0] * ssl[0];
#pragma unroll
    for (int h = 1; h < 5; ++h) a += M[g][h] * ssl[h];
    v[g] = a;
  }

  // local scores
  float a[NJ];
#pragma unroll
  for (int k = 0; k < NJ; ++k) {
    float x = s[k][0] * v[0];
#pragma unroll
    for (int g = 1; g < 5; ++g) x += s[k][g] * v[g];
    a[k] = x;
  }
  a[NJ - 1] = lastv ? a[NJ - 1] : -3.0e38f;

  float ml = a[0];
#pragma unroll
  for (int k = 1; k < NJ; ++k) ml = fmaxf(ml, a[k]);

  float d = 0.f, p[5] = {0.f, 0.f, 0.f, 0.f, 0.f};
#pragma unroll
  for (int k = 0; k < NJ; ++k) {
    float e = __expf(a[k] - ml);  // masked k: exp(-huge) = 0
    d += e;
#pragma unroll
    for (int g = 0; g < 5; ++g) p[g] += e * s[k][g];
  }

  // cross-q online-softmax merge
  float m1 = fmaxf(ml, __shfl_xor(ml, 16, 64));
  float m  = fmaxf(m1, __shfl_xor(m1, 32, 64));
  float c = __expf(ml - m);
  d *= c;
  d += __shfl_xor(d, 16, 64);
  d += __shfl_xor(d, 32, 64);
  float inv = 1.0f / d;

  float pool[5];
#pragma unroll
  for (int g = 0; g < 5; ++g) {
    float pg = p[g] * c;
    pg += __shfl_xor(pg, 16, 64);
    pg += __shfl_xor(pg, 32, 64);
    pool[g] = pg * inv;
  }
  if (q == 0) {
#pragma unroll
    for (int g = 0; g < 5; ++g) ob[OUTOFF + g] = pool[g];
  }
}

// LDS (floats): buf0 @0, buf1 @6240, buf2 @12480 (1560 fl4 each, chunk c ->
// buf c%3); outbuf @18720 (2 x 560 fl). Total 79360 B -> 2 blocks/CU.
__global__ __launch_bounds__(256, 2) void meso_kernel(
    const float* __restrict__ x, const float* __restrict__ w,
    float* __restrict__ out) {
  __shared__ __align__(16) float smf[19840];
  float4* sm4 = (float4*)smf;
  const int t = threadIdx.x;
  const int wv = t >> 6, ln = t & 63, q = ln >> 4, r = ln & 15;
  const size_t blk = blockIdx.x;
  const float4* xp4 = (const float4*)x + blk * 24960;  // 256*390/4
  float4* o4 = (float4*)out + blk * 2240;              // 256*35/4

  // M = W W^T: uniform scalar loads, consumed before the pipelined loop.
  float W[5][10];
#pragma unroll
  for (int g = 0; g < 5; ++g)
#pragma unroll
    for (int h = 0; h < 10; ++h) W[g][h] = w[g * 10 + h];
  float M[5][5];
#pragma unroll
  for (int g = 0; g < 5; ++g)
#pragma unroll
    for (int gp = 0; gp < 5; ++gp) {
      float a = 0.f;
#pragma unroll
      for (int h = 0; h < 10; ++h) a += W[g][h] * W[gp][h];
      M[g][gp] = a;
    }

  auto stage = [&](int c, int b) {
    const float4* g = xp4 + c * 1560;
    float4* l = sm4 + b * 1560;
#pragma unroll
    for (int i = 0; i < 6; ++i) GLL16(g + i * 256 + t, l + i * 256 + t);
    if (t < 24) GLL16(g + 1536 + t, l + 1536 + t);
  };

  stage(0, 0);
  stage(1, 1);

  int bcur = 0;  // p % 3
#pragma unroll 1
  for (int p = 0; p < 16; ++p) {
    // Exact per-wave counted wait for chunk p (wave0 issues 7 loads/chunk,
    // waves1-3 issue 6; every wave issues 1 flush store/phase from p>=1).
    if (p < 2) {
      if (wv == 0) asm volatile("s_waitcnt vmcnt(7)" ::: "memory");
      else         asm volatile("s_waitcnt vmcnt(6)" ::: "memory");
    } else if (p == 2) {
      if (wv == 0) asm volatile("s_waitcnt vmcnt(8)" ::: "memory");
      else         asm volatile("s_waitcnt vmcnt(7)" ::: "memory");
    } else if (p < 15) {
      if (wv == 0) asm volatile("s_waitcnt vmcnt(9)" ::: "memory");
      else         asm volatile("s_waitcnt vmcnt(8)" ::: "memory");
    } else {
      asm volatile("s_waitcnt vmcnt(2)" ::: "memory");
    }
    asm volatile("s_waitcnt lgkmcnt(0)" ::: "memory");
    __builtin_amdgcn_s_barrier();
    // Invariants: chunk p in buf[p%3]; compute(p-1) reads drained (so
    // buf[(p+2)%3] reusable); outbuf[(p-1)&1] complete.

    if (p < 14) {
      int bn = bcur + 2; if (bn >= 3) bn -= 3;
      stage(p + 2, bn);
    }
    if (p > 0 && ln < 35) {
      o4[(size_t)(p - 1) * 140 + wv * 35 + ln] =
          sm4[4680 + ((p - 1) & 1) * 140 + wv * 35 + ln];
    }

    {
      const float* bp = smf + bcur * 6240 + r * 390;
      float* ob = smf + 18720 + (p & 1) * 560 + r * 35;
      if (wv == 0) {
        seg64<25, 115, 15>(bp, q, M, ob);
      } else if (wv == 1) {
        seg64<12, 330, 30>(bp, q, M, ob);
        seg64<5,  0,   0 >(bp, q, M, ob);
      } else if (wv == 2) {
        seg64<9,  25,  5 >(bp, q, M, ob);
        seg64<9,  70,  10>(bp, q, M, ob);
      } else {
        seg64<9,  240, 20>(bp, q, M, ob);
        seg64<9,  285, 25>(bp, q, M, ob);
      }
    }
    ++bcur; if (bcur >= 3) bcur = 0;
  }

  asm volatile("s_waitcnt lgkmcnt(0)" ::: "memory");
  __builtin_amdgcn_s_barrier();
  if (ln < 35)
    o4[15 * 140 + wv * 35 + ln] = sm4[4680 + 140 + wv * 35 + ln];
}

extern "C" void kernel_launch(void* const* d_in, const int* in_sizes, int n_in,
                              void* d_out, int out_size, void* d_ws, size_t ws_size,
                              hipStream_t stream) {
  const float* x = (const float*)d_in[0];
  const float* w = (const float*)d_in[1];
  float* out = (float*)d_out;
  int B = in_sizes[0] / 390;  // 131072
  int grid = B / 256;         // 512 blocks = 2/CU, all resident
  meso_kernel<<<grid, 256, 0, stream>>>(x, w, out);
}